// Round 12
// baseline (2670.003 us; speedup 1.0000x reference)
//
#include <hip/hip_runtime.h>
#include <math.h>

// BWNet scan v12: single-exchange step.
// v10's proven counter-gated atomic fan-in kept for sweep partials (the ONLY
// cross-block exchange). The ri0 exchange is DELETED: ar is fully replicated
// in LDS (deterministic identical updates per block from the global pick), and
// each block redundantly recomputes the full ri0 = relu(W_a0@ar + c0)
// (256x1024 GEMV, ~1-1.5us: 1024 FMA + 256 L2-resident v4f loads per thread)
// -- cheaper than the ~2.5-3us exchange round it replaces.
// Everything else is v10 verbatim: tid0-only counter polls + s_sleep,
// __syncthreads chain, zero-role overlap, cent from read-only keys,
// 4-rows/thread ar update with W_a3 from L2.

typedef float v4f __attribute__((ext_vector_type(4)));
typedef unsigned long long ull;

#define N_ENT 8192
#define EMB   256
#define KD    32
#define ARD   1024
#define UT    233
#define NSCAN 32
#define NZERO 224
#define NBLK  256

// workspace float-index offsets
#define WS_KEYS 0         // 32*8192 floats, k-major: keys[k*8192+j]
#define WS_C0   262144    // 256: b_a0 + relu(W_fe@um + b_fe)
#define WS_PAIR 262400    // ull region (byte 1049600, 8B aligned)
// ull indices within the pair region
#define PR_CPART 0        // 64: partials completion counters
#define PR_KMAX  64       // 64: encoded argmax (v_bits<<32 | (0xFFFFFFFF-idx))
#define PR_SACC  128      // 32 ulls = 64 floats: S accumulators
#define NPAIRS   160

struct Params {
  const float *um, *emask, *enc, *arin, *W_fe, *b_fe, *W_k, *b_k,
              *W_a0, *b_a0, *W_a1, *b_a1, *W_f, *b_f, *W_i0, *b_i0,
              *W_i1, *b_i1, *W_o, *b_o, *ln_g, *ln_b, *W_a3, *b_a3;
  const int* ct;
  float* out;
  float* wsf;
  int*   wsi;
};

__device__ __forceinline__ ull ld_pair(ull* p_) {
  return __hip_atomic_load(p_, __ATOMIC_RELAXED, __HIP_MEMORY_SCOPE_AGENT);
}
__device__ __forceinline__ void wait_ctr(ull* c, ull target) {
  int guard = 0;
  while (__hip_atomic_load(c, __ATOMIC_RELAXED, __HIP_MEMORY_SCOPE_AGENT) < target) {
    __builtin_amdgcn_s_sleep(1);
    if (++guard > (1 << 20)) break;  // failsafe: never hang
  }
}

// ---------------- init: keys GEMM, func_embed, pair-region zero ----------------
__global__ __launch_bounds__(256) void k_init(Params p) {
  __shared__ float enc_s[32 * 260];
  __shared__ float um_s[UT];
  const int tid = threadIdx.x, bid = blockIdx.x;
  float* keys = p.wsf + WS_KEYS;

  if (bid == 0 && tid < UT) um_s[tid] = p.um[tid];
  if (bid == 3) {  // zero counters, Kmax, S accumulators
    ull* pr = (ull*)(p.wsf + WS_PAIR);
    for (int i = tid; i < NPAIRS; i += 256) pr[i] = 0ull;
  }

  const int j0 = bid * 32;
  #pragma unroll
  for (int i = 0; i < 8; ++i) {
    int idx = i * 256 + tid;
    int row = idx >> 6, c4 = idx & 63;
    v4f v = *(const v4f*)(p.enc + (size_t)(j0 + row) * EMB + c4 * 4);
    *(v4f*)&enc_s[row * 260 + c4 * 4] = v;
  }
  __syncthreads();
  {
    const int jl = tid >> 3, kg = tid & 7;
    float acc[4];
    #pragma unroll
    for (int kk = 0; kk < 4; ++kk) acc[kk] = p.b_k[kg * 4 + kk];
    for (int e4 = 0; e4 < 64; ++e4) {
      v4f x = *(const v4f*)&enc_s[jl * 260 + e4 * 4];
      #pragma unroll
      for (int kk = 0; kk < 4; ++kk) {
        v4f w = *(const v4f*)(p.W_k + (size_t)(kg * 4 + kk) * EMB + e4 * 4);
        acc[kk] += x.x * w.x + x.y * w.y + x.z * w.z + x.w * w.w;
      }
    }
    const int j = j0 + jl;
    #pragma unroll
    for (int kk = 0; kk < 4; ++kk) keys[(size_t)(kg * 4 + kk) * N_ENT + j] = acc[kk];
  }
  if (bid == 0) {
    float a = p.b_fe[tid];
    const float* wr = p.W_fe + (size_t)tid * UT;
    for (int u = 0; u < UT; ++u) a += wr[u] * um_s[u];
    p.wsf[WS_C0 + tid] = fmaxf(a, 0.f) + p.b_a0[tid];
  }
}

// ---------------- main: scan (blocks 0..31) + output zeroing (32..255) ----------------
__global__ __launch_bounds__(256, 1) void k_scan(Params p) {
  const int tid = threadIdx.x, bid = blockIdx.x;
  int ctv = p.ct[0];
  const int steps = ctv < 0 ? 0 : (ctv > 64 ? 64 : ctv);
  const size_t NN = (size_t)N_ENT * N_ENT;

  if (bid >= NSCAN) {  // -------- zero role (overlaps the scan; proven) --------
    v4f z = (v4f){0.f, 0.f, 0.f, 0.f};
    v4f* o4 = (v4f*)p.out;
    const size_t tot = NN / 4;
    for (size_t i = (size_t)steps * (N_ENT / 4) + (size_t)(bid - NSCAN) * 256 + tid;
         i < tot; i += (size_t)NZERO * 256)
      __builtin_nontemporal_store(z, o4 + i);
    return;
  }

  // -------- scan role --------
  __shared__ float ar_s[32 * 33];        // replicated full ar
  __shared__ float ri0_s[8 * 33];        // full ri0, recomputed locally per step
  __shared__ float c0_s[256];
  __shared__ unsigned maskb[256], selb[256];
  __shared__ float x_i1[32], q_s[32], h_s[32], qnf[32];
  __shared__ float garr[128], fog[32], rem[32], og[32], cent[32];
  __shared__ float b_a1s[32], gb_s[128], lng_s[32], lnb_s[32];
  __shared__ float reds[4], rmaxs[4];
  __shared__ int   ridxs[4];
  __shared__ float ssum_s;
  __shared__ int   upd_s, done_s;

  ull*   pairb = (ull*)(p.wsf + WS_PAIR);
  ull*   cpart = pairb + PR_CPART;
  ull*   kmaxp = pairb + PR_KMAX;
  float* saccp = (float*)(pairb + PR_SACC);
  const float* keys = p.wsf + WS_KEYS;

  // ---- preamble: replicated state + weights into LDS / registers ----
  for (int i = tid; i < ARD; i += 256) ar_s[(i >> 5) * 33 + (i & 31)] = p.arin[i];
  c0_s[tid] = p.wsf[WS_C0 + tid];
  {
    unsigned mb = 0u;
    const float* em = p.emask + (size_t)tid * 32;
    #pragma unroll
    for (int j = 0; j < 32; ++j) mb |= (em[j] != 0.f) ? (1u << j) : 0u;
    maskb[tid] = mb; selb[tid] = 0u;
  }
  if (tid < 32) {
    b_a1s[tid] = p.b_a1[tid];
    lng_s[tid] = p.ln_g[tid]; lnb_s[tid] = p.ln_b[tid];
    q_s[tid] = 0.f; h_s[tid] = 0.f; qnf[tid] = 0.f; x_i1[tid] = 0.f;
  }
  if (tid < 128) {
    const int g = tid >> 5, r = tid & 31;
    const float* bg = (g == 0) ? p.b_f : (g == 1) ? p.b_i0 : (g == 2) ? p.b_i1 : p.b_o;
    gb_s[tid] = bg[r];
  }
  if (tid == 0) done_s = 0;

  v4f w1[8];  // W_a1: thread = (row tid>>3, cols (tid&7)*32..+32)
  { const float* s = p.W_a1 + (size_t)(tid >> 3) * EMB + (tid & 7) * 32;
    #pragma unroll
    for (int i = 0; i < 8; ++i) w1[i] = ((const v4f*)s)[i]; }
  v4f wg[8];  // LSTM gates: 128 rows x 2 halves
  { const int rowg = tid >> 1, g = rowg >> 5, r = rowg & 31, half = tid & 1;
    const float* W = (g == 0) ? p.W_f : (g == 1) ? p.W_i0 : (g == 2) ? p.W_i1 : p.W_o;
    const float* s = W + r * 64 + half * 32;
    #pragma unroll
    for (int i = 0; i < 8; ++i) wg[i] = ((const v4f*)s)[i]; }
  float kc[32];  // this thread's key column, register-resident
  { const int gcol = bid * 256 + tid;
    #pragma unroll
    for (int k = 0; k < 32; ++k) kc[k] = keys[(size_t)k * N_ENT + gcol]; }
  __syncthreads();

  // redundant full-ri0 recompute: 256 rows x 1024 cols, 8 threads/row.
  // thread: rows (tid>>3)+32*pass, cols (tid&7)*128..+128 (ar seg in regs).
  auto recompute_ri0 = [&]() {
    const int seg = tid & 7, r0 = tid >> 3;
    v4f arseg[32];
    #pragma unroll
    for (int i = 0; i < 32; ++i) {
      const int c = seg * 128 + 4 * i;
      const float* a = &ar_s[(c >> 5) * 33 + (c & 31)];
      arseg[i] = (v4f){a[0], a[1], a[2], a[3]};
    }
    #pragma unroll
    for (int pass = 0; pass < 8; ++pass) {
      const int r = r0 + 32 * pass;
      const float* wrow = p.W_a0 + (size_t)r * ARD + seg * 128;
      float pa = 0.f;
      #pragma unroll
      for (int i = 0; i < 32; ++i) {
        v4f wv = ((const v4f*)wrow)[i];
        pa += wv.x * arseg[i].x + wv.y * arseg[i].y + wv.z * arseg[i].z + wv.w * arseg[i].w;
      }
      pa += __shfl_xor(pa, 1);
      pa += __shfl_xor(pa, 2);
      pa += __shfl_xor(pa, 4);
      if (seg == 0) ri0_s[(r >> 5) * 33 + (r & 31)] = fmaxf(pa + c0_s[r], 0.f);
    }
  };
  recompute_ri0();   // ri0 for step 0 (no exchange needed)
  __syncthreads();

  float v_reg = 0.f;
  for (int t = 0; t < steps; ++t) {
    const int act = (done_s == 0);

    // ==== LSTM chain (v10 verbatim; ri0_s is local) ====
    {  // i1 = relu(W_a1 @ ri0 + b_a1)
      const int r = tid >> 3, s8 = tid & 7;
      float p1 = 0.f;
      #pragma unroll
      for (int i = 0; i < 8; ++i) {
        const float* xx = &ri0_s[s8 * 33 + 4 * i];
        p1 += w1[i].x * xx[0] + w1[i].y * xx[1] + w1[i].z * xx[2] + w1[i].w * xx[3];
      }
      #pragma unroll
      for (int m = 4; m; m >>= 1) p1 += __shfl_xor(p1, m);
      if (s8 == 0) x_i1[r] = fmaxf(p1 + b_a1s[r], 0.f);
    }
    __syncthreads();
    {  // 4 gate pre-activations
      const int rowg = tid >> 1, g = rowg >> 5, half = tid & 1;
      const float* xsrc = half ? q_s : x_i1;  // x = concat(i1, q)
      float pg = 0.f;
      #pragma unroll
      for (int i = 0; i < 8; ++i)
        pg += wg[i].x * xsrc[4 * i] + wg[i].y * xsrc[4 * i + 1] +
              wg[i].z * xsrc[4 * i + 2] + wg[i].w * xsrc[4 * i + 3];
      pg += __shfl_xor(pg, 1);
      if (!half) {
        pg += gb_s[rowg];
        garr[rowg] = (g == 2) ? tanhf(pg) : 1.f / (1.f + __expf(-pg));
      }
    }
    __syncthreads();
    {  // 3 layernorms in parallel (one per wave)
      const int w = tid >> 6, k = tid & 63;
      if (w < 3 && k < 32) {
        float a = (w == 0) ? garr[k] : (w == 1) ? garr[32 + k] * garr[64 + k] : garr[96 + k];
        float s = a;
        #pragma unroll
        for (int m = 16; m; m >>= 1) s += __shfl_xor(s, m);
        const float mean = s * (1.f / 32.f);
        const float d = a - mean;
        float vv = d * d;
        #pragma unroll
        for (int m = 16; m; m >>= 1) vv += __shfl_xor(vv, m);
        vv *= (1.f / 32.f);
        const float y = d * rsqrtf(vv + 1e-5f) * lng_s[k] + lnb_s[k];
        if (w == 0) fog[k] = y; else if (w == 1) rem[k] = y; else og[k] = y;
      }
    }
    __syncthreads();
    if (tid < 32) {
      const float nh = rem[tid] + fog[tid] * h_s[tid];
      const float qv = tanhf(nh) * og[tid];
      qnf[tid] = qv;
      if (act) { h_s[tid] = nh; q_s[tid] = qv; }
    }
    __syncthreads();

    // ==== Phase S: sweep over this block's 256 register-resident key cols ====
    {
      float dot = 0.f;
      #pragma unroll
      for (int k = 0; k < 32; ++k) dot += qnf[k] * kc[k];
      const float sig = 1.f / (1.f + __expf(-dot));
      const float v = __expf(__logf(sig) / 0.8f);  // sig^(1/TEMP)
      v_reg = v;
      float sv = v, mv = v;
      int mi = (bid << 8) + tid;
      #pragma unroll
      for (int m = 32; m; m >>= 1) {
        sv += __shfl_xor(sv, m);
        const float ov = __shfl_xor(mv, m);
        const int oi = __shfl_xor(mi, m);
        if (ov > mv || (ov == mv && oi < mi)) { mv = ov; mi = oi; }
      }
      const int wv = tid >> 6;
      if ((tid & 63) == 0) { reds[wv] = sv; rmaxs[wv] = mv; ridxs[wv] = mi; }
    }
    __syncthreads();
    if (tid == 0) {  // atomic fan-in: S add, argmax max, drain, bump, wait
      float Sb = ((reds[0] + reds[1]) + reds[2]) + reds[3];
      float Mb = rmaxs[0]; int Ib = ridxs[0];
      #pragma unroll
      for (int i2 = 1; i2 < 4; ++i2)
        if (rmaxs[i2] > Mb || (rmaxs[i2] == Mb && ridxs[i2] < Ib)) { Mb = rmaxs[i2]; Ib = ridxs[i2]; }
      __hip_atomic_fetch_add(&saccp[t], Sb, __ATOMIC_RELAXED, __HIP_MEMORY_SCOPE_AGENT);
      const ull key = ((ull)__float_as_uint(Mb) << 32) | (ull)(0xFFFFFFFFu - (unsigned)Ib);
      __hip_atomic_fetch_max(&kmaxp[t], key, __ATOMIC_RELAXED, __HIP_MEMORY_SCOPE_AGENT);
      asm volatile("s_waitcnt vmcnt(0)" ::: "memory");  // data before flag
      __hip_atomic_fetch_add(&cpart[t], 1ull, __ATOMIC_RELAXED, __HIP_MEMORY_SCOPE_AGENT);
      wait_ctr(&cpart[t], (ull)NSCAN);
    }
    __syncthreads();

    // ==== Phase B: read 2 lines -> cent gather -> flags -> ar -> recompute ====
    if (tid < 32) {
      const float s = __hip_atomic_load(&saccp[t], __ATOMIC_RELAXED, __HIP_MEMORY_SCOPE_AGENT);
      const ull km = ld_pair(&kmaxp[t]);
      const int ii = (int)(0xFFFFFFFFu - (unsigned)(km & 0xFFFFFFFFull));
      const float kv = keys[(size_t)tid * N_ENT + ii];  // keys[:, pick], read-only
      float mn = kv;
      #pragma unroll
      for (int mm = 16; mm; mm >>= 1) mn += __shfl_xor(mn, mm);
      mn *= (1.f / 32.f);
      const float cv = kv - mn;
      cent[tid] = cv;
      const unsigned long long bb = __ballot(cv != cv);
      if (tid == 0) {
        const int valid = (s != 0.f);
        const int nf = (bb == 0) ? 1 : 0;
        const unsigned mw = maskb[ii >> 5];
        const int hit = (act && valid && ((mw >> (ii & 31)) & 1)) ? 1 : 0;
        ssum_s = s;
        upd_s = (hit && nf) ? 1 : 0;
        if (hit) {
          maskb[ii >> 5] = mw & ~(1u << (ii & 31));
          selb[ii >> 5] |= (1u << (ii & 31));
          if (!nf) done_s = 1;
        }
      }
    }
    __syncthreads();
    {  // row write for step t (this block's 256 columns)
      const float S = ssum_s;
      const float rowv = (act && (S != 0.f)) ? (v_reg / S) : 0.f;
      __builtin_nontemporal_store(rowv, p.out + (size_t)t * N_ENT + (bid << 8) + tid);
    }
    if (upd_s) {  // replicated ar update: 4 rows/thread, W_a3 from L2
      #pragma unroll
      for (int rr = 0; rr < 4; ++rr) {
        const int r = tid + rr * 256;
        const float* wr = p.W_a3 + (size_t)r * KD;
        float dl = p.b_a3[r];
        #pragma unroll
        for (int c4 = 0; c4 < 8; ++c4) {
          v4f wv4 = *(const v4f*)(wr + 4 * c4);
          dl += wv4.x * cent[4 * c4] + wv4.y * cent[4 * c4 + 1] +
                wv4.z * cent[4 * c4 + 2] + wv4.w * cent[4 * c4 + 3];
        }
        if (dl > 0.f) ar_s[(r >> 5) * 33 + (r & 31)] += dl;
      }
    }
    __syncthreads();
    recompute_ri0();   // ri0 for step t+1, fully local
    __syncthreads();
  }
  __syncthreads();

  // ==== epilogue: sel_out and ar_out (replicated state) ====
  if (bid == 0) {
    for (int i = tid; i < N_ENT; i += 256)
      p.out[NN + i] = ((selb[i >> 5] >> (i & 31)) & 1u) ? 1.f : 0.f;
  } else if (bid == 1) {
    for (int i = tid; i < ARD; i += 256)
      p.out[NN + N_ENT + i] = ar_s[(i >> 5) * 33 + (i & 31)];
  }
}

extern "C" void kernel_launch(void* const* d_in, const int* in_sizes, int n_in,
                              void* d_out, int out_size, void* d_ws, size_t ws_size,
                              hipStream_t stream) {
  (void)in_sizes; (void)n_in; (void)out_size; (void)ws_size;
  Params p;
  p.um    = (const float*)d_in[0];
  p.emask = (const float*)d_in[1];
  p.enc   = (const float*)d_in[2];
  p.arin  = (const float*)d_in[3];
  p.W_fe  = (const float*)d_in[4];
  p.b_fe  = (const float*)d_in[5];
  p.W_k   = (const float*)d_in[6];
  p.b_k   = (const float*)d_in[7];
  p.W_a0  = (const float*)d_in[8];
  p.b_a0  = (const float*)d_in[9];
  p.W_a1  = (const float*)d_in[10];
  p.b_a1  = (const float*)d_in[11];
  p.W_f   = (const float*)d_in[12];
  p.b_f   = (const float*)d_in[13];
  p.W_i0  = (const float*)d_in[14];
  p.b_i0  = (const float*)d_in[15];
  p.W_i1  = (const float*)d_in[16];
  p.b_i1  = (const float*)d_in[17];
  p.W_o   = (const float*)d_in[18];
  p.b_o   = (const float*)d_in[19];
  p.ln_g  = (const float*)d_in[20];
  p.ln_b  = (const float*)d_in[21];
  p.W_a3  = (const float*)d_in[22];
  p.b_a3  = (const float*)d_in[23];
  p.ct    = (const int*)d_in[24];
  p.out   = (float*)d_out;
  p.wsf   = (float*)d_ws;
  p.wsi   = (int*)d_ws;

  hipLaunchKernelGGL(k_init, dim3(NBLK), dim3(256), 0, stream, p);
  hipLaunchKernelGGL(k_scan, dim3(NBLK), dim3(256), 0, stream, p);
}

// Round 13
// 890.107 us; speedup vs baseline: 2.9996x; 2.9996x over previous
//
#include <hip/hip_runtime.h>
#include <math.h>

// BWNet scan v13: v10's proven counter-gated atomic fan-in exchange, with
// NSCAN 32 -> 16 (halve RMW serialization on the counter lines + straggler
// pool). Each scan block: 512 key columns in registers (2 sets), 16 ri0 rows.
// Everything else v10 verbatim: tid0-gated s_sleep polls, atomicAdd(S) +
// atomicMax(key) + bump, cent from read-only keys, 4 rows/thread ar update,
// zero-role overlap (240 blocks).

typedef float v4f __attribute__((ext_vector_type(4)));
typedef unsigned long long ull;

#define N_ENT 8192
#define EMB   256
#define KD    32
#define ARD   1024
#define UT    233
#define NSCAN 16
#define NZERO 240
#define NBLK  256

// workspace float-index offsets
#define WS_KEYS 0         // 32*8192 floats, k-major: keys[k*8192+j]
#define WS_C0   262144    // 256: b_a0 + relu(W_fe@um + b_fe)
#define WS_PAIR 262400    // ull region (byte 1049600, 8B aligned)
// ull indices within the pair region
#define PR_RI0W  0        // 2*256: ri0 value words, ping-pong by step parity
#define PR_CRI0  512      // 65: ri0 completion counters (step t)
#define PR_CPART 577      // 64: partials completion counters
#define PR_KMAX  641      // 64: encoded argmax (v_bits<<32 | (0xFFFFFFFF-idx))
#define PR_SACC  705      // 32 ulls = 64 floats: S accumulators
#define NPAIRS   737

struct Params {
  const float *um, *emask, *enc, *arin, *W_fe, *b_fe, *W_k, *b_k,
              *W_a0, *b_a0, *W_a1, *b_a1, *W_f, *b_f, *W_i0, *b_i0,
              *W_i1, *b_i1, *W_o, *b_o, *ln_g, *ln_b, *W_a3, *b_a3;
  const int* ct;
  float* out;
  float* wsf;
  int*   wsi;
};

__device__ __forceinline__ ull ld_pair(ull* p_) {
  return __hip_atomic_load(p_, __ATOMIC_RELAXED, __HIP_MEMORY_SCOPE_AGENT);
}
__device__ __forceinline__ void st_pair(ull* p_, ull v) {
  __hip_atomic_store(p_, v, __ATOMIC_RELAXED, __HIP_MEMORY_SCOPE_AGENT);
}
__device__ __forceinline__ void wait_ctr(ull* c, ull target) {
  int guard = 0;
  while (__hip_atomic_load(c, __ATOMIC_RELAXED, __HIP_MEMORY_SCOPE_AGENT) < target) {
    __builtin_amdgcn_s_sleep(1);
    if (++guard > (1 << 20)) break;  // failsafe: never hang
  }
}

// ---------------- init: keys GEMM, func_embed, pair-region zero ----------------
__global__ __launch_bounds__(256) void k_init(Params p) {
  __shared__ float enc_s[32 * 260];
  __shared__ float um_s[UT];
  const int tid = threadIdx.x, bid = blockIdx.x;
  float* keys = p.wsf + WS_KEYS;

  if (bid == 0 && tid < UT) um_s[tid] = p.um[tid];
  if (bid == 3) {  // zero ri0 slots, counters, Kmax, S accumulators
    ull* pr = (ull*)(p.wsf + WS_PAIR);
    for (int i = tid; i < NPAIRS; i += 256) pr[i] = 0ull;
  }

  const int j0 = bid * 32;
  #pragma unroll
  for (int i = 0; i < 8; ++i) {
    int idx = i * 256 + tid;
    int row = idx >> 6, c4 = idx & 63;
    v4f v = *(const v4f*)(p.enc + (size_t)(j0 + row) * EMB + c4 * 4);
    *(v4f*)&enc_s[row * 260 + c4 * 4] = v;
  }
  __syncthreads();
  {
    const int jl = tid >> 3, kg = tid & 7;
    float acc[4];
    #pragma unroll
    for (int kk = 0; kk < 4; ++kk) acc[kk] = p.b_k[kg * 4 + kk];
    for (int e4 = 0; e4 < 64; ++e4) {
      v4f x = *(const v4f*)&enc_s[jl * 260 + e4 * 4];
      #pragma unroll
      for (int kk = 0; kk < 4; ++kk) {
        v4f w = *(const v4f*)(p.W_k + (size_t)(kg * 4 + kk) * EMB + e4 * 4);
        acc[kk] += x.x * w.x + x.y * w.y + x.z * w.z + x.w * w.w;
      }
    }
    const int j = j0 + jl;
    #pragma unroll
    for (int kk = 0; kk < 4; ++kk) keys[(size_t)(kg * 4 + kk) * N_ENT + j] = acc[kk];
  }
  if (bid == 0) {
    float a = p.b_fe[tid];
    const float* wr = p.W_fe + (size_t)tid * UT;
    for (int u = 0; u < UT; ++u) a += wr[u] * um_s[u];
    p.wsf[WS_C0 + tid] = fmaxf(a, 0.f) + p.b_a0[tid];
  }
}

// ---------------- main: scan (blocks 0..15) + output zeroing (16..255) ----------------
__global__ __launch_bounds__(256, 1) void k_scan(Params p) {
  const int tid = threadIdx.x, bid = blockIdx.x;
  int ctv = p.ct[0];
  const int steps = ctv < 0 ? 0 : (ctv > 64 ? 64 : ctv);
  const size_t NN = (size_t)N_ENT * N_ENT;

  if (bid >= NSCAN) {  // -------- zero role (overlaps the scan; proven) --------
    v4f z = (v4f){0.f, 0.f, 0.f, 0.f};
    v4f* o4 = (v4f*)p.out;
    const size_t tot = NN / 4;
    for (size_t i = (size_t)steps * (N_ENT / 4) + (size_t)(bid - NSCAN) * 256 + tid;
         i < tot; i += (size_t)NZERO * 256)
      __builtin_nontemporal_store(z, o4 + i);
    return;
  }

  // -------- scan role --------
  __shared__ float ar_s[32 * 33];
  __shared__ float ri0_s[8 * 33];
  __shared__ unsigned maskb[256], selb[256];
  __shared__ float x_i1[32], q_s[32], h_s[32], qnf[32];
  __shared__ float garr[128], fog[32], rem[32], og[32], cent[32];
  __shared__ float b_a1s[32], gb_s[128], lng_s[32], lnb_s[32], c0own[16];
  __shared__ float reds[4], rmaxs[4];
  __shared__ int   ridxs[4];
  __shared__ float ssum_s;
  __shared__ int   upd_s, done_s;

  ull*   pairb = (ull*)(p.wsf + WS_PAIR);
  ull*   ri0w  = pairb + PR_RI0W;
  ull*   cri0  = pairb + PR_CRI0;
  ull*   cpart = pairb + PR_CPART;
  ull*   kmaxp = pairb + PR_KMAX;
  float* saccp = (float*)(pairb + PR_SACC);
  const float* keys = p.wsf + WS_KEYS;

  // ---- preamble: replicated state + weights into LDS / registers ----
  for (int i = tid; i < ARD; i += 256) ar_s[(i >> 5) * 33 + (i & 31)] = p.arin[i];
  {
    unsigned mb = 0u;
    const float* em = p.emask + (size_t)tid * 32;
    #pragma unroll
    for (int j = 0; j < 32; ++j) mb |= (em[j] != 0.f) ? (1u << j) : 0u;
    maskb[tid] = mb; selb[tid] = 0u;
  }
  if (tid < 32) {
    b_a1s[tid] = p.b_a1[tid];
    lng_s[tid] = p.ln_g[tid]; lnb_s[tid] = p.ln_b[tid];
    q_s[tid] = 0.f; h_s[tid] = 0.f; qnf[tid] = 0.f; x_i1[tid] = 0.f;
  }
  if (tid < 128) {
    const int g = tid >> 5, r = tid & 31;
    const float* bg = (g == 0) ? p.b_f : (g == 1) ? p.b_i0 : (g == 2) ? p.b_i1 : p.b_o;
    gb_s[tid] = bg[r];
  }
  if (tid < 16) c0own[tid] = p.wsf[WS_C0 + bid * 16 + tid];
  if (tid == 0) done_s = 0;

  v4f w0[16]; // W_a0 rows [16b,16b+16): thread = (row tid>>4, cols (tid&15)*64..+64)
  { const float* s = p.W_a0 + (size_t)(bid * 16 + (tid >> 4)) * ARD + (tid & 15) * 64;
    #pragma unroll
    for (int i = 0; i < 16; ++i) w0[i] = ((const v4f*)s)[i]; }
  v4f w1[8];  // W_a1: thread = (row tid>>3, cols (tid&7)*32..+32)
  { const float* s = p.W_a1 + (size_t)(tid >> 3) * EMB + (tid & 7) * 32;
    #pragma unroll
    for (int i = 0; i < 8; ++i) w1[i] = ((const v4f*)s)[i]; }
  v4f wg[8];  // LSTM gates: 128 rows x 2 halves
  { const int rowg = tid >> 1, g = rowg >> 5, r = rowg & 31, half = tid & 1;
    const float* W = (g == 0) ? p.W_f : (g == 1) ? p.W_i0 : (g == 2) ? p.W_i1 : p.W_o;
    const float* s = W + r * 64 + half * 32;
    #pragma unroll
    for (int i = 0; i < 8; ++i) wg[i] = ((const v4f*)s)[i]; }
  float kc0[32], kc1[32];  // this thread's TWO key columns, register-resident
  { const int g0 = bid * 512 + tid, g1 = g0 + 256;
    #pragma unroll
    for (int k = 0; k < 32; ++k) {
      kc0[k] = keys[(size_t)k * N_ENT + g0];
      kc1[k] = keys[(size_t)k * N_ENT + g1];
    } }
  __syncthreads();

  // produce ri0 rows [16b,16b+16) for step tt into slot[tt&1]
  auto produce = [&](int tt) {
    const int r = tid >> 4, seg = tid & 15;
    float pa = 0.f;
    #pragma unroll
    for (int i = 0; i < 16; ++i) {
      const int c = seg * 64 + 4 * i;
      const float* a = &ar_s[(c >> 5) * 33 + (c & 31)];
      pa += w0[i].x * a[0] + w0[i].y * a[1] + w0[i].z * a[2] + w0[i].w * a[3];
    }
    pa += __shfl_xor(pa, 1);
    pa += __shfl_xor(pa, 2);
    pa += __shfl_xor(pa, 4);
    pa += __shfl_xor(pa, 8);
    if (seg == 0)
      st_pair(&ri0w[(tt & 1) * 256 + bid * 16 + r],
              (ull)__float_as_uint(fmaxf(pa + c0own[r], 0.f)));
  };
  produce(0);
  __syncthreads();  // drains vmcnt -> ri0 stores visible before counter bump
  if (tid == 0)
    __hip_atomic_fetch_add(&cri0[0], 1ull, __ATOMIC_RELAXED, __HIP_MEMORY_SCOPE_AGENT);

  float v_reg0 = 0.f, v_reg1 = 0.f;
  for (int t = 0; t < steps; ++t) {
    // ==== Phase A: wait ri0 counter -> batch read -> LSTM chain ====
    if (tid == 0) wait_ctr(&cri0[t], (ull)NSCAN);
    __syncthreads();
    {
      ull u = ld_pair(&ri0w[(t & 1) * 256 + tid]);
      ri0_s[(tid >> 5) * 33 + (tid & 31)] = __uint_as_float((unsigned)u);
    }
    __syncthreads();
    const int act = (done_s == 0);
    {  // i1 = relu(W_a1 @ ri0 + b_a1)
      const int r = tid >> 3, s8 = tid & 7;
      float p1 = 0.f;
      #pragma unroll
      for (int i = 0; i < 8; ++i) {
        const float* xx = &ri0_s[s8 * 33 + 4 * i];
        p1 += w1[i].x * xx[0] + w1[i].y * xx[1] + w1[i].z * xx[2] + w1[i].w * xx[3];
      }
      #pragma unroll
      for (int m = 4; m; m >>= 1) p1 += __shfl_xor(p1, m);
      if (s8 == 0) x_i1[r] = fmaxf(p1 + b_a1s[r], 0.f);
    }
    __syncthreads();
    {  // 4 gate pre-activations
      const int rowg = tid >> 1, g = rowg >> 5, half = tid & 1;
      const float* xsrc = half ? q_s : x_i1;  // x = concat(i1, q)
      float pg = 0.f;
      #pragma unroll
      for (int i = 0; i < 8; ++i)
        pg += wg[i].x * xsrc[4 * i] + wg[i].y * xsrc[4 * i + 1] +
              wg[i].z * xsrc[4 * i + 2] + wg[i].w * xsrc[4 * i + 3];
      pg += __shfl_xor(pg, 1);
      if (!half) {
        pg += gb_s[rowg];
        garr[rowg] = (g == 2) ? tanhf(pg) : 1.f / (1.f + __expf(-pg));
      }
    }
    __syncthreads();
    {  // 3 layernorms in parallel (one per wave)
      const int w = tid >> 6, k = tid & 63;
      if (w < 3 && k < 32) {
        float a = (w == 0) ? garr[k] : (w == 1) ? garr[32 + k] * garr[64 + k] : garr[96 + k];
        float s = a;
        #pragma unroll
        for (int m = 16; m; m >>= 1) s += __shfl_xor(s, m);
        const float mean = s * (1.f / 32.f);
        const float d = a - mean;
        float vv = d * d;
        #pragma unroll
        for (int m = 16; m; m >>= 1) vv += __shfl_xor(vv, m);
        vv *= (1.f / 32.f);
        const float y = d * rsqrtf(vv + 1e-5f) * lng_s[k] + lnb_s[k];
        if (w == 0) fog[k] = y; else if (w == 1) rem[k] = y; else og[k] = y;
      }
    }
    __syncthreads();
    if (tid < 32) {
      const float nh = rem[tid] + fog[tid] * h_s[tid];
      const float qv = tanhf(nh) * og[tid];
      qnf[tid] = qv;
      if (act) { h_s[tid] = nh; q_s[tid] = qv; }
    }
    __syncthreads();

    // ==== Phase S: sweep over this block's 512 register-resident key cols ====
    {
      float dot0 = 0.f, dot1 = 0.f;
      #pragma unroll
      for (int k = 0; k < 32; ++k) {
        const float q = qnf[k];
        dot0 += q * kc0[k];
        dot1 += q * kc1[k];
      }
      const float v0 = __expf(__logf(1.f / (1.f + __expf(-dot0))) / 0.8f);
      const float v1 = __expf(__logf(1.f / (1.f + __expf(-dot1))) / 0.8f);
      v_reg0 = v0; v_reg1 = v1;
      // idx0 = bid*512+tid < idx1 = idx0+256, so strict > picks v1 (ties keep idx0)
      float sv = v0 + v1, mv = v0;
      int mi = bid * 512 + tid;
      if (v1 > v0) { mv = v1; mi += 256; }
      #pragma unroll
      for (int m = 32; m; m >>= 1) {
        sv += __shfl_xor(sv, m);
        const float ov = __shfl_xor(mv, m);
        const int oi = __shfl_xor(mi, m);
        if (ov > mv || (ov == mv && oi < mi)) { mv = ov; mi = oi; }
      }
      const int wv = tid >> 6;
      if ((tid & 63) == 0) { reds[wv] = sv; rmaxs[wv] = mv; ridxs[wv] = mi; }
    }
    __syncthreads();
    if (tid == 0) {  // atomic fan-in: S add, argmax max, then counter bump
      float Sb = ((reds[0] + reds[1]) + reds[2]) + reds[3];
      float Mb = rmaxs[0]; int Ib = ridxs[0];
      #pragma unroll
      for (int i2 = 1; i2 < 4; ++i2)
        if (rmaxs[i2] > Mb || (rmaxs[i2] == Mb && ridxs[i2] < Ib)) { Mb = rmaxs[i2]; Ib = ridxs[i2]; }
      __hip_atomic_fetch_add(&saccp[t], Sb, __ATOMIC_RELAXED, __HIP_MEMORY_SCOPE_AGENT);
      const ull key = ((ull)__float_as_uint(Mb) << 32) | (ull)(0xFFFFFFFFu - (unsigned)Ib);
      __hip_atomic_fetch_max(&kmaxp[t], key, __ATOMIC_RELAXED, __HIP_MEMORY_SCOPE_AGENT);
      asm volatile("s_waitcnt vmcnt(0)" ::: "memory");  // data before flag
      __hip_atomic_fetch_add(&cpart[t], 1ull, __ATOMIC_RELAXED, __HIP_MEMORY_SCOPE_AGENT);
    }

    // ==== Phase B: one-line wait -> 2-line read -> keys gather -> flags ====
    if (tid == 0) wait_ctr(&cpart[t], (ull)NSCAN);
    __syncthreads();
    if (tid < 32) {
      const float s = __hip_atomic_load(&saccp[t], __ATOMIC_RELAXED, __HIP_MEMORY_SCOPE_AGENT);
      const ull km = ld_pair(&kmaxp[t]);
      const int ii = (int)(0xFFFFFFFFu - (unsigned)(km & 0xFFFFFFFFull));
      const float kv = keys[(size_t)tid * N_ENT + ii];  // keys[:, pick], read-only
      float mn = kv;
      #pragma unroll
      for (int mm = 16; mm; mm >>= 1) mn += __shfl_xor(mn, mm);
      mn *= (1.f / 32.f);
      const float cv = kv - mn;
      cent[tid] = cv;
      const unsigned long long bb = __ballot(cv != cv);
      if (tid == 0) {
        const int valid = (s != 0.f);
        const int nf = (bb == 0) ? 1 : 0;
        const unsigned mw = maskb[ii >> 5];
        const int hit = (act && valid && ((mw >> (ii & 31)) & 1)) ? 1 : 0;
        ssum_s = s;
        upd_s = (hit && nf) ? 1 : 0;
        if (hit) {
          maskb[ii >> 5] = mw & ~(1u << (ii & 31));
          selb[ii >> 5] |= (1u << (ii & 31));
          if (!nf) done_s = 1;
        }
      }
    }
    __syncthreads();
    {  // row write for step t (this block's 512 columns)
      const float S = ssum_s;
      const int av = (act && (S != 0.f)) ? 1 : 0;
      float* orow = p.out + (size_t)t * N_ENT + bid * 512;
      __builtin_nontemporal_store(av ? (v_reg0 / S) : 0.f, orow + tid);
      __builtin_nontemporal_store(av ? (v_reg1 / S) : 0.f, orow + 256 + tid);
    }
    if (upd_s) {  // replicated ar update: 4 rows/thread, W_a3 from L2
      #pragma unroll
      for (int rr = 0; rr < 4; ++rr) {
        const int r = tid + rr * 256;
        const float* wr = p.W_a3 + (size_t)r * KD;
        float dl = p.b_a3[r];
        #pragma unroll
        for (int c4 = 0; c4 < 8; ++c4) {
          v4f wv4 = *(const v4f*)(wr + 4 * c4);
          dl += wv4.x * cent[4 * c4] + wv4.y * cent[4 * c4 + 1] +
                wv4.z * cent[4 * c4 + 2] + wv4.w * cent[4 * c4 + 3];
        }
        if (dl > 0.f) ar_s[(r >> 5) * 33 + (r & 31)] += dl;
      }
    }
    __syncthreads();
    produce(t + 1);   // ri0 for step t+1 into slot[(t+1)&1]
    __syncthreads();  // drains vmcnt -> slice visible before counter bump
    if (tid == 0)
      __hip_atomic_fetch_add(&cri0[t + 1], 1ull, __ATOMIC_RELAXED, __HIP_MEMORY_SCOPE_AGENT);
  }
  __syncthreads();

  // ==== epilogue: sel_out and ar_out (replicated state) ====
  if (bid == 0) {
    for (int i = tid; i < N_ENT; i += 256)
      p.out[NN + i] = ((selb[i >> 5] >> (i & 31)) & 1u) ? 1.f : 0.f;
  } else if (bid == 1) {
    for (int i = tid; i < ARD; i += 256)
      p.out[NN + N_ENT + i] = ar_s[(i >> 5) * 33 + (i & 31)];
  }
}

extern "C" void kernel_launch(void* const* d_in, const int* in_sizes, int n_in,
                              void* d_out, int out_size, void* d_ws, size_t ws_size,
                              hipStream_t stream) {
  (void)in_sizes; (void)n_in; (void)out_size; (void)ws_size;
  Params p;
  p.um    = (const float*)d_in[0];
  p.emask = (const float*)d_in[1];
  p.enc   = (const float*)d_in[2];
  p.arin  = (const float*)d_in[3];
  p.W_fe  = (const float*)d_in[4];
  p.b_fe  = (const float*)d_in[5];
  p.W_k   = (const float*)d_in[6];
  p.b_k   = (const float*)d_in[7];
  p.W_a0  = (const float*)d_in[8];
  p.b_a0  = (const float*)d_in[9];
  p.W_a1  = (const float*)d_in[10];
  p.b_a1  = (const float*)d_in[11];
  p.W_f   = (const float*)d_in[12];
  p.b_f   = (const float*)d_in[13];
  p.W_i0  = (const float*)d_in[14];
  p.b_i0  = (const float*)d_in[15];
  p.W_i1  = (const float*)d_in[16];
  p.b_i1  = (const float*)d_in[17];
  p.W_o   = (const float*)d_in[18];
  p.b_o   = (const float*)d_in[19];
  p.ln_g  = (const float*)d_in[20];
  p.ln_b  = (const float*)d_in[21];
  p.W_a3  = (const float*)d_in[22];
  p.b_a3  = (const float*)d_in[23];
  p.ct    = (const int*)d_in[24];
  p.out   = (float*)d_out;
  p.wsf   = (float*)d_ws;
  p.wsi   = (int*)d_ws;

  hipLaunchKernelGGL(k_init, dim3(NBLK), dim3(256), 0, stream, p);
  hipLaunchKernelGGL(k_scan, dim3(NBLK), dim3(256), 0, stream, p);
}